// Round 16
// baseline (92.660 us; speedup 1.0000x reference)
//
#include <hip/hip_runtime.h>

#define T_LEN  1048576
#define NROWS  32
#define NTAPS  128
#define N2     32
#define BLOCK  256
#define NCH    11             /* K chunks of 16: k = m + 129 - 16c - s */
#define W_OUT  2048           /* outputs per wave (2 MFMA tiles) */
#define BPR    128            /* blocks per row */
#define W_Q4   548            /* float4 loads per wave (2192 elems) */
#define XH_W_BYTES 4416       /* 276 padded 16B chunks (274 used) */
#define WAVE_BYTES XH_W_BYTES /* epilogue buffer ALIASES stage bytes 0..4095 */
#define SMEM_BYTES (4 * WAVE_BYTES)             /* 17664 */

typedef __attribute__((ext_vector_type(8)))  _Float16 half8;
typedef __attribute__((ext_vector_type(2)))  __fp16   fp16x2;
typedef __attribute__((ext_vector_type(16))) float    f32x16;
typedef __attribute__((ext_vector_type(4)))  float    f32x4;

__device__ __forceinline__ int swz16(int q) { return q ^ ((q >> 3) & 7); }

// ---- kernel 1: impulse response h[0..127] (+D at 0); fp16 Toeplitz A-frags ----
// A_c[m,s] = h[m + 129 - 16c - s], lane=(m=lane&31, g=lane>>5), s=8g+i
__global__ __launch_bounds__(NTAPS) void ssm_taps(
    const float* __restrict__ w_real, const float* __restrict__ w_imag,
    const float* __restrict__ log_dt,
    const float* __restrict__ C_real, const float* __restrict__ C_imag,
    const float* __restrict__ B_real, const float* __restrict__ B_imag,
    const float* __restrict__ Dp, float* __restrict__ ws) {
  __shared__ float hsh[NTAPS];
  const int k = threadIdx.x;
  const float dt = expf(log_dt[0]);
  const float kf = (float)k;
  float acc = 0.f;
  for (int n = 0; n < N2; ++n) {
    const float a  = dt * w_real[n];
    const float b  = dt * w_imag[n];
    const float cr = C_real[n], ci = C_imag[n];
    const float br = B_real[n], bi = B_imag[n];
    const float coef_r = cr * br - ci * bi;
    const float coef_i = cr * bi + ci * br;
    const float e = expf(a * kf);
    float s, c;
    sincosf(b * kf, &s, &c);
    acc += e * (coef_r * c - coef_i * s);
  }
  if (k == 0) acc += Dp[0];
  ws[k]  = acc;                              // plain h (exact tail)
  hsh[k] = acc;
  __syncthreads();
  if (k < 64) {
    _Float16* AH = (_Float16*)(ws + NTAPS);
    const int m = k & 31, g = k >> 5;
    for (int c = 0; c < NCH; ++c)
      for (int i = 0; i < 8; ++i) {
        const int idx = m + 129 - 16 * c - 8 * g - i;
        const float v = (idx >= 0 && idx < NTAPS) ? hsh[idx] : 0.f;
        AH[(c * 64 + k) * 8 + i] = (_Float16)v;   // RNE
      }
  }
}

// ---- kernel 2: barrier-free implicit-GEMM FIR, two 32x32 tiles per wave.
//      Wave-private fp16 stage; epilogue buffer aliases the stage region
//      (same-wave LDS ops are in-order -> no barrier needed); 8 blocks/CU. ----
__global__ __launch_bounds__(BLOCK, 8) void ssm_conv(
    const float* __restrict__ x, const float* __restrict__ ws,
    float* __restrict__ out) {
  __shared__ __align__(16) unsigned char smem[SMEM_BYTES];
  const int tid  = threadIdx.x;
  const int lane = tid & 63;
  const int wid  = tid >> 6;
  const int p    = lane & 31, g = lane >> 5;
  const int row  = blockIdx.x >> 7;          // 128 blocks per row
  const int jb   = blockIdx.x & 127;
  const int W0   = jb * (4 * W_OUT) + wid * W_OUT;   // wave's output base
  const float* __restrict__ xrow = x + (size_t)row * T_LEN;

  char*  xw   = (char*)smem + wid * WAVE_BYTES;      // wave-private stage
  float* ebuf = (float*)xw;                          // epi aliases stage

  // issue the 9 long-latency x loads FIRST
  float4 xf[9];
#pragma unroll
  for (int j = 0; j < 9; ++j) {
    const int q4 = lane + 64 * j;
    if (q4 < W_Q4) {
      int gfi = W0 - 256 + 4 * q4;           // clamp left edge (tail re-fixes)
      gfi = gfi < 0 ? 0 : gfi;
      xf[j] = *(const float4*)(xrow + gfi);
    }
  }
  // A fragments -> VGPRs (L2-hot) overlap the x-load latency
  half8 A[NCH];
  const half8* __restrict__ wsA = (const half8*)(ws + NTAPS);
#pragma unroll
  for (int c = 0; c < NCH; ++c) A[c] = wsA[c * 64 + lane];

  // cvt + swizzled ds_write (staged e <-> x[W0 - 256 + e])
#pragma unroll
  for (int j = 0; j < 9; ++j) {
    const int q4 = lane + 64 * j;
    if (q4 < W_Q4) {
      const fp16x2 a = __builtin_amdgcn_cvt_pkrtz(xf[j].x, xf[j].y);
      const fp16x2 b = __builtin_amdgcn_cvt_pkrtz(xf[j].z, xf[j].w);
      uint2 w;
      w.x = __builtin_bit_cast(unsigned, a);
      w.y = __builtin_bit_cast(unsigned, b);
      *(uint2*)(xw + swz16(q4 >> 1) * 16 + (q4 & 1) * 8) = w;
    }
  }

  // compute: 2 tiles x 11 x { ds_read_b128 + MFMA } (in-order after writes)
  const int qb = 4 * p + g;                  // lane's fp16-chunk base
  f32x16 acc0 = {}, acc1 = {};
#pragma unroll
  for (int c = 0; c < NCH; ++c) {
    const half8 B0 = *(const half8*)(xw + swz16(qb + 2 * c) * 16);
    acc0 = __builtin_amdgcn_mfma_f32_32x32x16_f16(A[c], B0, acc0, 0, 0, 0);
    const half8 B1 = *(const half8*)(xw + swz16(qb + 128 + 2 * c) * 16);
    acc1 = __builtin_amdgcn_mfma_f32_32x32x16_f16(A[c], B1, acc1, 0, 0, 0);
  }

  // epilogue per tile into the (now dead) stage region: [32 pc][8 qm] quad
  // grid, XOR-swizzled -> conflict-free; 4 coalesced NT dwordx4 stores.
  // Same-wave in-order LDS guarantees writes land after all B-reads above.
#pragma unroll
  for (int tt = 0; tt < 2; ++tt) {
    const f32x16& acc = tt ? acc1 : acc0;
#pragma unroll
    for (int k = 0; k < 4; ++k) {            // quad r=4k..4k+3: m=8k+4g+j, col p
      const int q = p * 8 + 2 * k + g;
      float4 v;
      v.x = acc[4 * k];     v.y = acc[4 * k + 1];
      v.z = acc[4 * k + 2]; v.w = acc[4 * k + 3];
      *(float4*)(ebuf + (q ^ (p & 7)) * 4) = v;
    }
    float* __restrict__ obase = out + (size_t)row * T_LEN + W0 + tt * 1024;
#pragma unroll
    for (int pp = 0; pp < 4; ++pp) {
      const int o  = 4 * lane + 256 * pp;    // outputs o..o+3 (o = 32*pc + m)
      const int pc = o >> 5;
      const int q  = pc * 8 + (lane & 7);
      const f32x4 v = *(const f32x4*)(ebuf + (q ^ (pc & 7)) * 4);
      __builtin_nontemporal_store(v, (f32x4*)(obase + o));
    }
  }

  // merged exact fp32 tail: first block of each row rewrites n in [0,254)
  if (jb == 0) {
    __syncthreads();                         // drains this block's stores
    const float* __restrict__ h = ws;
    if (tid < 254) {
      float a = 0.f;
      if (tid < 127) {                       // circular wraparound region
        for (int k = tid + 1; k < NTAPS; ++k)
          a += h[k] * xrow[T_LEN + tid - k];
      } else {                               // causal with zero left-pad
        for (int k = 0; k <= tid - 127; ++k)
          a += h[k] * xrow[tid - 127 - k];
      }
      out[(size_t)row * T_LEN + tid] = a;
    }
  }
}

extern "C" void kernel_launch(void* const* d_in, const int* in_sizes, int n_in,
                              void* d_out, int out_size, void* d_ws, size_t ws_size,
                              hipStream_t stream) {
  const float* x      = (const float*)d_in[0];
  const float* w_real = (const float*)d_in[1];
  const float* w_imag = (const float*)d_in[2];
  const float* log_dt = (const float*)d_in[3];
  const float* C_real = (const float*)d_in[4];
  const float* C_imag = (const float*)d_in[5];
  const float* B_real = (const float*)d_in[6];
  const float* B_imag = (const float*)d_in[7];
  const float* Dp     = (const float*)d_in[8];
  float* out = (float*)d_out;
  float* ws  = (float*)d_ws;   // 128 f32 h + NCH*64*8 fp16 A-frags = 11.8 KB

  ssm_taps<<<1, NTAPS, 0, stream>>>(w_real, w_imag, log_dt,
                                    C_real, C_imag, B_real, B_imag, Dp, ws);
  ssm_conv<<<NROWS * BPR, BLOCK, 0, stream>>>(x, ws, out);
}

// Round 17
// 63.142 us; speedup vs baseline: 1.4675x; 1.4675x over previous
//
#include <hip/hip_runtime.h>

#define T_LEN  1048576
#define NROWS  32
#define NTAPS  128
#define N2     32
#define BLOCK  256
#define NCH    11             /* K chunks of 16: k = m + 129 - 16c - s */
#define W_OUT  2048           /* outputs per wave (2 MFMA tiles) */
#define BPR    128            /* blocks per row */
#define W_Q4   548            /* float4 loads per wave (2192 elems) */
#define A_LDS_BYTES 11264     /* 11 chunks x 1024 B */
#define XH_W_BYTES 4416       /* 276 padded 16B chunks (274 used); epi aliases */
#define SMEM_BYTES (A_LDS_BYTES + 4 * XH_W_BYTES)   /* 28928 */

typedef __attribute__((ext_vector_type(8)))  _Float16 half8;
typedef __attribute__((ext_vector_type(2)))  __fp16   fp16x2;
typedef __attribute__((ext_vector_type(16))) float    f32x16;
typedef __attribute__((ext_vector_type(4)))  float    f32x4;

__device__ __forceinline__ int swz16(int q) { return q ^ ((q >> 3) & 7); }

// ---- kernel 1: impulse response h[0..127] (+D at 0); fp16 Toeplitz A-frags ----
// A_c[m,s] = h[m + 129 - 16c - s], lane=(m=lane&31, g=lane>>5), s=8g+i
__global__ __launch_bounds__(NTAPS) void ssm_taps(
    const float* __restrict__ w_real, const float* __restrict__ w_imag,
    const float* __restrict__ log_dt,
    const float* __restrict__ C_real, const float* __restrict__ C_imag,
    const float* __restrict__ B_real, const float* __restrict__ B_imag,
    const float* __restrict__ Dp, float* __restrict__ ws) {
  __shared__ float hsh[NTAPS];
  const int k = threadIdx.x;
  const float dt = expf(log_dt[0]);
  const float kf = (float)k;
  float acc = 0.f;
  for (int n = 0; n < N2; ++n) {
    const float a  = dt * w_real[n];
    const float b  = dt * w_imag[n];
    const float cr = C_real[n], ci = C_imag[n];
    const float br = B_real[n], bi = B_imag[n];
    const float coef_r = cr * br - ci * bi;
    const float coef_i = cr * bi + ci * br;
    const float e = expf(a * kf);
    float s, c;
    sincosf(b * kf, &s, &c);
    acc += e * (coef_r * c - coef_i * s);
  }
  if (k == 0) acc += Dp[0];
  ws[k]  = acc;                              // plain h (exact tail)
  hsh[k] = acc;
  __syncthreads();
  if (k < 64) {
    _Float16* AH = (_Float16*)(ws + NTAPS);
    const int m = k & 31, g = k >> 5;
    for (int c = 0; c < NCH; ++c)
      for (int i = 0; i < 8; ++i) {
        const int idx = m + 129 - 16 * c - 8 * g - i;
        const float v = (idx >= 0 && idx < NTAPS) ? hsh[idx] : 0.f;
        AH[(c * 64 + k) * 8 + i] = (_Float16)v;   // RNE
      }
  }
}

// ---- kernel 2: implicit-GEMM FIR, two 32x32 tiles per wave.
//      A-fragments DMA'd to LDS once per block (kills 11 VMEM instrs/wave);
//      wave-private fp16 x-stage; one barrier; aliased epilogue; NT stores. ----
__global__ __launch_bounds__(BLOCK, 5) void ssm_conv(
    const float* __restrict__ x, const float* __restrict__ ws,
    float* __restrict__ out) {
  __shared__ __align__(16) unsigned char smem[SMEM_BYTES];
  char* Al = (char*)smem;                    // block-shared A (11 KB)
  const int tid  = threadIdx.x;
  const int lane = tid & 63;
  const int wid  = tid >> 6;
  const int p    = lane & 31, g = lane >> 5;
  const int row  = blockIdx.x >> 7;          // 128 blocks per row
  const int jb   = blockIdx.x & 127;
  const int W0   = jb * (4 * W_OUT) + wid * W_OUT;   // wave's output base
  const float* __restrict__ xrow = x + (size_t)row * T_LEN;

  char*  xw   = (char*)smem + A_LDS_BYTES + wid * XH_W_BYTES;  // wave stage
  float* ebuf = (float*)xw;                                    // epi aliases

  // (1) DMA A-fragments into LDS: chunk c = 64 lanes x 16 B, dest linear.
  const _Float16* gA = (const _Float16*)(ws + NTAPS);
  for (int c = wid; c < NCH; c += 4) {
    __builtin_amdgcn_global_load_lds(
        (const __attribute__((address_space(1))) void*)(gA + (c * 64 + lane) * 8),
        (__attribute__((address_space(3))) void*)(Al + c * 1024), 16, 0, 0);
  }

  // (2) stage wave's 2192-elem window as fp16 (staged e <-> x[W0 - 256 + e])
#pragma unroll
  for (int j = 0; j < 9; ++j) {
    const int q4 = lane + 64 * j;            // float4 index within window
    if (q4 < W_Q4) {
      int gfi = W0 - 256 + 4 * q4;           // clamp left edge (tail re-fixes)
      gfi = gfi < 0 ? 0 : gfi;
      const float4 f = *(const float4*)(xrow + gfi);
      const fp16x2 a = __builtin_amdgcn_cvt_pkrtz(f.x, f.y);
      const fp16x2 b = __builtin_amdgcn_cvt_pkrtz(f.z, f.w);
      uint2 w;
      w.x = __builtin_bit_cast(unsigned, a);
      w.y = __builtin_bit_cast(unsigned, b);
      *(uint2*)(xw + swz16(q4 >> 1) * 16 + (q4 & 1) * 8) = w;
    }
  }

  __syncthreads();                           // A ready (drains vmcnt+lgkm)

  // (3) A-fragments LDS -> VGPRs: 11 conflict-free ds_read_b128
  half8 A[NCH];
#pragma unroll
  for (int c = 0; c < NCH; ++c)
    A[c] = *(const half8*)(Al + c * 1024 + lane * 16);

  // (4) compute: 2 tiles x 11 x { ds_read_b128 + MFMA }
  const int qb = 4 * p + g;                  // lane's fp16-chunk base
  f32x16 acc0 = {}, acc1 = {};
#pragma unroll
  for (int c = 0; c < NCH; ++c) {
    const half8 B0 = *(const half8*)(xw + swz16(qb + 2 * c) * 16);
    acc0 = __builtin_amdgcn_mfma_f32_32x32x16_f16(A[c], B0, acc0, 0, 0, 0);
    const half8 B1 = *(const half8*)(xw + swz16(qb + 128 + 2 * c) * 16);
    acc1 = __builtin_amdgcn_mfma_f32_32x32x16_f16(A[c], B1, acc1, 0, 0, 0);
  }

  // (5) epilogue per tile into the (now dead) stage region: [32 pc][8 qm]
  // quad grid, XOR-swizzled -> conflict-free; 4 coalesced NT stores/tile.
  // Same-wave in-order LDS: writes land after all B-reads above.
#pragma unroll
  for (int tt = 0; tt < 2; ++tt) {
    const f32x16& acc = tt ? acc1 : acc0;
#pragma unroll
    for (int k = 0; k < 4; ++k) {            // quad r=4k..4k+3: m=8k+4g+j, col p
      const int q = p * 8 + 2 * k + g;
      float4 v;
      v.x = acc[4 * k];     v.y = acc[4 * k + 1];
      v.z = acc[4 * k + 2]; v.w = acc[4 * k + 3];
      *(float4*)(ebuf + (q ^ (p & 7)) * 4) = v;
    }
    float* __restrict__ obase = out + (size_t)row * T_LEN + W0 + tt * 1024;
#pragma unroll
    for (int pp = 0; pp < 4; ++pp) {
      const int o  = 4 * lane + 256 * pp;    // outputs o..o+3 (o = 32*pc + m)
      const int pc = o >> 5;
      const int q  = pc * 8 + (lane & 7);
      const f32x4 v = *(const f32x4*)(ebuf + (q ^ (pc & 7)) * 4);
      __builtin_nontemporal_store(v, (f32x4*)(obase + o));
    }
  }

  // merged exact fp32 tail: first block of each row rewrites n in [0,254)
  if (jb == 0) {
    __syncthreads();                         // orders wave-0 stores before tail
    const float* __restrict__ h = ws;
    if (tid < 254) {
      float a = 0.f;
      if (tid < 127) {                       // circular wraparound region
        for (int k = tid + 1; k < NTAPS; ++k)
          a += h[k] * xrow[T_LEN + tid - k];
      } else {                               // causal with zero left-pad
        for (int k = 0; k <= tid - 127; ++k)
          a += h[k] * xrow[tid - 127 - k];
      }
      out[(size_t)row * T_LEN + tid] = a;
    }
  }
}

extern "C" void kernel_launch(void* const* d_in, const int* in_sizes, int n_in,
                              void* d_out, int out_size, void* d_ws, size_t ws_size,
                              hipStream_t stream) {
  const float* x      = (const float*)d_in[0];
  const float* w_real = (const float*)d_in[1];
  const float* w_imag = (const float*)d_in[2];
  const float* log_dt = (const float*)d_in[3];
  const float* C_real = (const float*)d_in[4];
  const float* C_imag = (const float*)d_in[5];
  const float* B_real = (const float*)d_in[6];
  const float* B_imag = (const float*)d_in[7];
  const float* Dp     = (const float*)d_in[8];
  float* out = (float*)d_out;
  float* ws  = (float*)d_ws;   // 128 f32 h + NCH*64*8 fp16 A-frags = 11.8 KB

  ssm_taps<<<1, NTAPS, 0, stream>>>(w_real, w_imag, log_dt,
                                    C_real, C_imag, B_real, B_imag, Dp, ws);
  ssm_conv<<<NROWS * BPR, BLOCK, 0, stream>>>(x, ws, out);
}